// Round 17
// baseline (798.848 us; speedup 1.0000x reference)
//
#include <hip/hip_runtime.h>
#include <hip/hip_fp16.h>

typedef _Float16 f16x8 __attribute__((ext_vector_type(8)));
typedef float f32x4 __attribute__((ext_vector_type(4)));

#define N_PTS 32768

// ---- prep: repack W2 + b2 into f16 MFMA fragment layout (proven R6 version)
// chunk c, frag q = s*4 + nt: wsB[c*4096 + (q*64+lane)*8 + j] =
//   Wf[c*64 + s*32 + ((lane>>4)&3)*8 + j][nt*16 + (lane&15)]
__global__ __launch_bounds__(256) void prep_kernel(
    const float* __restrict__ W2, const float* __restrict__ b2,
    _Float16* __restrict__ wsB) {
  __shared__ _Float16 w_lds[64][72];
  const int c   = blockIdx.x;
  const int tid = threadIdx.x;
  {
    const float* src = (c < 64) ? (W2 + c * 4096 + tid * 16) : (b2 + tid * 16);
    int kl = tid >> 2, o = (tid & 3) * 16;
    f16x8 v0, v1;
    #pragma unroll
    for (int j = 0; j < 8; ++j) {
      v0[j] = (_Float16)src[j];
      v1[j] = (_Float16)src[8 + j];
    }
    *(f16x8*)(&w_lds[kl][o])     = v0;
    *(f16x8*)(&w_lds[kl][o + 8]) = v1;
  }
  __syncthreads();
  #pragma unroll
  for (int u = 0; u < 2; ++u) {
    int t = tid + u * 256;
    int q = t >> 6, lane = t & 63;
    int klbase = (q >> 2) * 32 + ((lane >> 4) & 3) * 8;
    int o      = (q & 3) * 16 + (lane & 15);
    f16x8 v;
    #pragma unroll
    for (int j = 0; j < 8; ++j) v[j] = w_lds[klbase + j][o];
    *(f16x8*)(wsB + c * 4096 + t * 8) = v;
  }
}

// gelu (tanh form) helper
__device__ inline float gelu_t(float v) {
  float v2 = v * v;
  float u  = v * fmaf(0.044715f, v2, 1.0f);
  float e  = __builtin_amdgcn_exp2f(u * 2.3022084f);
  float rr = e + 1.0f;
  float inv;
  asm("v_rcp_f32 %0, %1" : "=v"(inv) : "v"(rr));
  return v * (1.0f - inv);
}

// ===== mainA: 128-row blocks, waves = 4-way K-split x 2-way col-split =====
// 256 blocks x 512 threads. B L2 traffic: 256 x 520 KB = 133 MB (half of R12).
// REP=3 measurement loop around {B loads, K-loop, reduce, store} (idempotent).
__global__ __launch_bounds__(512) void mainA_kernel(
    const float* __restrict__ x, const float* __restrict__ gridp,
    const float* __restrict__ W1, const float* __restrict__ b1,
    const _Float16* __restrict__ wsB, float* __restrict__ out) {

  __shared__ _Float16 h_t[4][128][16];     // 16384 B: h_t[ks][row][p] = h[row][ks+4p]
  __shared__ float part[2][128][68];       // 69632 B; total 86016 -> 1 block/CU
  _Float16* x_lds = (_Float16*)&part[0][0][0];   // [128][72] f16; dead before part

  const int tid  = threadIdx.x;
  const int lane = tid & 63;
  const int wave = tid >> 6;
  const int ks   = wave & 3;         // K-split: c = ks + 4p
  const int ns   = wave >> 2;        // col half: cols [32ns, 32ns+32)
  const int rowblk = blockIdx.x * 128;
  const int mrow = lane & 15;
  const int kgrp = lane >> 4;

  // x stage: 512 threads x 16 f32 -> f16 -> x_lds
  {
    const float* xsrc = x + rowblk * 64 + tid * 16;
    f32x4 a0 = *(const f32x4*)(xsrc),     a1 = *(const f32x4*)(xsrc + 4);
    f32x4 a2 = *(const f32x4*)(xsrc + 8), a3 = *(const f32x4*)(xsrc + 12);
    int row = tid >> 2, o = (tid & 3) * 16;
    f16x8 v0, v1;
    #pragma unroll
    for (int j = 0; j < 4; ++j) {
      v0[j] = (_Float16)a0[j]; v0[4 + j] = (_Float16)a1[j];
      v1[j] = (_Float16)a2[j]; v1[4 + j] = (_Float16)a3[j];
    }
    *(f16x8*)(&x_lds[row * 72 + o])     = v0;
    *(f16x8*)(&x_lds[row * 72 + o + 8]) = v1;
  }
  // h: thread (row = tid>>2, w4 = tid&3): k = w4 + 4q -> h_t[w4][row][q]
  {
    int row = tid >> 2, w4 = tid & 3;
    int r = rowblk + row;
    float g0 = gridp[r * 3 + 0], g1 = gridp[r * 3 + 1], g2 = gridp[r * 3 + 2];
    f16x8 h0, h1;
    #pragma unroll
    for (int q = 0; q < 16; ++q) {
      int k = w4 + 4 * q;
      float v = g0 * W1[k] + g1 * W1[64 + k] + g2 * W1[128 + k] + b1[k];
      float h = gelu_t(v);
      if (q < 8) h0[q] = (_Float16)h; else h1[q - 8] = (_Float16)h;
    }
    *(f16x8*)(&h_t[w4][row][0]) = h0;
    *(f16x8*)(&h_t[w4][row][8]) = h1;
  }
  __syncthreads();

  // pre-rep register state (x_lds is aliased by part -> must hoist)
  f16x8 xf[8][2];
  #pragma unroll
  for (int m = 0; m < 8; ++m)
    #pragma unroll
    for (int s = 0; s < 2; ++s)
      xf[m][s] = *(const f16x8*)(&x_lds[(m * 16 + mrow) * 72 + s * 32 + kgrp * 8]);
  f16x8 hreg[8][2];
  #pragma unroll
  for (int m = 0; m < 8; ++m) {
    hreg[m][0] = *(const f16x8*)(&h_t[ks][m * 16 + mrow][0]);
    hreg[m][1] = *(const f16x8*)(&h_t[ks][m * 16 + mrow][8]);
  }
  __syncthreads();   // everyone's x_lds reads done before rep-loop part writes

  const _Float16* bp = wsB + lane * 8;

  #pragma unroll 1
  for (int rep = 0; rep < 3; ++rep) {
    asm volatile("" ::: "memory");
    f16x8 bsl[2][4];   // 2-slot rotation x 4 frags (s*2+n), n = local col-tile
    // LOADB(slot, c): frag q = s*4 + 2ns + n
    #define LOADB_A(slot, c)                                                   \
      {                                                                        \
        _Pragma("unroll")                                                      \
        for (int s = 0; s < 2; ++s)                                            \
          _Pragma("unroll")                                                    \
          for (int n = 0; n < 2; ++n)                                          \
            bsl[slot][s * 2 + n] =                                             \
                *(const f16x8*)(bp + ((c) * 8 + s * 4 + 2 * ns + n) * 512);    \
      }
    LOADB_A(0, ks)
    LOADB_A(1, ks + 4)

    f32x4 acc[8][2];
    #pragma unroll
    for (int m = 0; m < 8; ++m)
      #pragma unroll
      for (int n = 0; n < 2; ++n)
        acc[m][n] = (f32x4){0.f, 0.f, 0.f, 0.f};

    #pragma unroll
    for (int p = 0; p < 16; ++p) {
      const int sl = p & 1;
      #pragma unroll
      for (int m = 0; m < 8; ++m) {
        _Float16 hh = hreg[m][p >> 3][p & 7];
        f16x8 hs = {hh, hh, hh, hh, hh, hh, hh, hh};
        f16x8 a0 = xf[m][0] * hs;
        f16x8 a1 = xf[m][1] * hs;
        #pragma unroll
        for (int n = 0; n < 2; ++n) {
          acc[m][n] = __builtin_amdgcn_mfma_f32_16x16x32_f16(a0, bsl[sl][n],     acc[m][n], 0, 0, 0);
          acc[m][n] = __builtin_amdgcn_mfma_f32_16x16x32_f16(a1, bsl[sl][2 + n], acc[m][n], 0, 0, 0);
        }
      }
      if (p + 2 < 16) { LOADB_A(sl, ks + 4 * (p + 2)) }
      else if (p + 2 == 16 && ks == 0) { LOADB_A(sl, 64) }   // bias chunk
    }
    if (ks == 0) {   // bias (h == 1) in slot 0
      #pragma unroll
      for (int m = 0; m < 8; ++m)
        #pragma unroll
        for (int n = 0; n < 2; ++n) {
          acc[m][n] = __builtin_amdgcn_mfma_f32_16x16x32_f16(xf[m][0], bsl[0][n],     acc[m][n], 0, 0, 0);
          acc[m][n] = __builtin_amdgcn_mfma_f32_16x16x32_f16(xf[m][1], bsl[0][2 + n], acc[m][n], 0, 0, 0);
        }
    }
    #undef LOADB_A

    __syncthreads();
    if (ks < 2) {          // stage 1: ks 0,1 write
      #pragma unroll
      for (int m = 0; m < 8; ++m)
        #pragma unroll
        for (int n = 0; n < 2; ++n)
          #pragma unroll
          for (int r = 0; r < 4; ++r)
            part[ks][m * 16 + kgrp * 4 + r][(2 * ns + n) * 16 + mrow] = acc[m][n][r];
    }
    __syncthreads();
    if (ks >= 2) {         // stage 2: ks 2,3 accumulate
      #pragma unroll
      for (int m = 0; m < 8; ++m)
        #pragma unroll
        for (int n = 0; n < 2; ++n)
          #pragma unroll
          for (int r = 0; r < 4; ++r)
            part[ks - 2][m * 16 + kgrp * 4 + r][(2 * ns + n) * 16 + mrow] += acc[m][n][r];
    }
    __syncthreads();
    {                      // stage 3: sum 2 buffers, store
      int row = tid >> 2, cb = (tid & 3) * 16;
      float* op = out + (rowblk + row) * 64 + cb;
      #pragma unroll
      for (int j = 0; j < 4; ++j) {
        f32x4 s = *(const f32x4*)(&part[0][row][cb + j * 4]);
        s += *(const f32x4*)(&part[1][row][cb + j * 4]);
        *(f32x4*)(op + j * 4) = s;
      }
    }
    __syncthreads();       // part fully read before next rep overwrites
  }
}

// ===== mainB: exact R12 structure (best known: 30.3 total), REP=3 =====
__global__ __launch_bounds__(256) void mainB_kernel(
    const float* __restrict__ x, const float* __restrict__ gridp,
    const float* __restrict__ W1, const float* __restrict__ b1,
    const _Float16* __restrict__ wsB, float* __restrict__ out) {

  __shared__ _Float16 h_t[4][64][16];          // 8192 B
  __shared__ float part[4][64 * 68];           // 69632 B
  _Float16* x_lds = (_Float16*)&part[0][0];    // [64][72]; dead before part

  const int tid  = threadIdx.x;
  const int lane = tid & 63;
  const int wave = tid >> 6;
  const int rowblk = blockIdx.x * 64;
  const int mrow = lane & 15;
  const int kgrp = lane >> 4;

  {
    const float* xsrc = x + rowblk * 64 + tid * 16;
    f32x4 a0 = *(const f32x4*)(xsrc),     a1 = *(const f32x4*)(xsrc + 4);
    f32x4 a2 = *(const f32x4*)(xsrc + 8), a3 = *(const f32x4*)(xsrc + 12);
    int row = tid >> 2, o = (tid & 3) * 16;
    f16x8 v0, v1;
    #pragma unroll
    for (int j = 0; j < 4; ++j) {
      v0[j] = (_Float16)a0[j]; v0[4 + j] = (_Float16)a1[j];
      v1[j] = (_Float16)a2[j]; v1[4 + j] = (_Float16)a3[j];
    }
    *(f16x8*)(&x_lds[row * 72 + o])     = v0;
    *(f16x8*)(&x_lds[row * 72 + o + 8]) = v1;
  }
  {
    int row = tid >> 2, w4 = tid & 3;
    int r = rowblk + row;
    float g0 = gridp[r * 3 + 0], g1 = gridp[r * 3 + 1], g2 = gridp[r * 3 + 2];
    f16x8 h0, h1;
    #pragma unroll
    for (int q = 0; q < 16; ++q) {
      int k = w4 + 4 * q;
      float v = g0 * W1[k] + g1 * W1[64 + k] + g2 * W1[128 + k] + b1[k];
      float h = gelu_t(v);
      if (q < 8) h0[q] = (_Float16)h; else h1[q - 8] = (_Float16)h;
    }
    *(f16x8*)(&h_t[w4][row][0]) = h0;
    *(f16x8*)(&h_t[w4][row][8]) = h1;
  }
  __syncthreads();

  f16x8 xf[4][2];
  #pragma unroll
  for (int m = 0; m < 4; ++m)
    #pragma unroll
    for (int s = 0; s < 2; ++s)
      xf[m][s] = *(const f16x8*)(&x_lds[(m * 16 + mrow) * 72 + s * 32 + kgrp * 8]);
  f16x8 hreg[4][2];
  #pragma unroll
  for (int m = 0; m < 4; ++m) {
    hreg[m][0] = *(const f16x8*)(&h_t[wave][m * 16 + mrow][0]);
    hreg[m][1] = *(const f16x8*)(&h_t[wave][m * 16 + mrow][8]);
  }
  __syncthreads();

  const _Float16* bp = wsB + lane * 8;

  #pragma unroll 1
  for (int rep = 0; rep < 3; ++rep) {
    asm volatile("" ::: "memory");
    f16x8 bA[8], bB[8], bC[8];
    #define LOADB_B(buf, c)                                                    \
      {                                                                        \
        _Pragma("unroll")                                                      \
        for (int q = 0; q < 8; ++q)                                            \
          buf[q] = *(const f16x8*)(bp + ((c) * 8 + q) * 512);                  \
      }
    LOADB_B(bA, wave)
    LOADB_B(bB, wave + 4)
    LOADB_B(bC, wave + 8)

    f32x4 acc[4][4];
    #pragma unroll
    for (int m = 0; m < 4; ++m)
      #pragma unroll
      for (int n = 0; n < 4; ++n)
        acc[m][n] = (f32x4){0.f, 0.f, 0.f, 0.f};

    auto COMPUTE = [&](const f16x8* b, int p) {
      #pragma unroll
      for (int m = 0; m < 4; ++m) {
        _Float16 hh = hreg[m][p >> 3][p & 7];
        f16x8 hs = {hh, hh, hh, hh, hh, hh, hh, hh};
        f16x8 a0 = xf[m][0] * hs;
        f16x8 a1 = xf[m][1] * hs;
        #pragma unroll
        for (int n = 0; n < 4; ++n) {
          acc[m][n] = __builtin_amdgcn_mfma_f32_16x16x32_f16(a0, b[n],     acc[m][n], 0, 0, 0);
          acc[m][n] = __builtin_amdgcn_mfma_f32_16x16x32_f16(a1, b[4 + n], acc[m][n], 0, 0, 0);
        }
      }
    };

    #pragma unroll
    for (int g = 0; g < 5; ++g) {
      COMPUTE(bA, 3 * g);
      if (3 * g + 3 < 16) LOADB_B(bA, wave + 4 * (3 * g + 3))
      COMPUTE(bB, 3 * g + 1);
      if (3 * g + 4 < 16) { LOADB_B(bB, wave + 4 * (3 * g + 4)) }
      else if (wave == 0) { LOADB_B(bB, 64) }
      COMPUTE(bC, 3 * g + 2);
      if (3 * g + 5 < 16) LOADB_B(bC, wave + 4 * (3 * g + 5))
    }
    COMPUTE(bA, 15);
    if (wave == 0) {
      #pragma unroll
      for (int m = 0; m < 4; ++m)
        #pragma unroll
        for (int n = 0; n < 4; ++n) {
          acc[m][n] = __builtin_amdgcn_mfma_f32_16x16x32_f16(xf[m][0], bB[n],     acc[m][n], 0, 0, 0);
          acc[m][n] = __builtin_amdgcn_mfma_f32_16x16x32_f16(xf[m][1], bB[4 + n], acc[m][n], 0, 0, 0);
        }
    }
    #undef LOADB_B

    __syncthreads();
    {
      float* pw = part[wave];
      #pragma unroll
      for (int m = 0; m < 4; ++m)
        #pragma unroll
        for (int n = 0; n < 4; ++n)
          #pragma unroll
          for (int r = 0; r < 4; ++r)
            pw[(m * 16 + kgrp * 4 + r) * 68 + n * 16 + mrow] = acc[m][n][r];
    }
    __syncthreads();
    {
      int row = tid >> 2, cb = (tid & 3) * 16;
      const float* p0 = part[0] + row * 68 + cb;
      float* op = out + (rowblk + row) * 64 + cb;
      #pragma unroll
      for (int j = 0; j < 4; ++j) {
        f32x4 s = *(const f32x4*)(p0 + j * 4);
        #pragma unroll
        for (int w = 1; w < 4; ++w)
          s += *(const f32x4*)(p0 + w * (64 * 68) + j * 4);
        *(f32x4*)(op + j * 4) = s;
      }
    }
    __syncthreads();
  }
}

extern "C" void kernel_launch(void* const* d_in, const int* in_sizes, int n_in,
                              void* d_out, int out_size, void* d_ws, size_t ws_size,
                              hipStream_t stream) {
  const float* x    = (const float*)d_in[0];
  const float* grid = (const float*)d_in[1];
  const float* W1   = (const float*)d_in[2];
  const float* b1   = (const float*)d_in[3];
  const float* W2   = (const float*)d_in[4];
  const float* b2   = (const float*)d_in[5];
  float* out = (float*)d_out;
  _Float16* wsB = (_Float16*)d_ws;   // 65*4096*2 = 532480 bytes

  hipLaunchKernelGGL(prep_kernel, dim3(65), dim3(256), 0, stream,
                     W2, b2, wsB);
  // A/B measurement: mainA (new 128-row col-split) then mainB (R12 baseline,
  // runs last -> final output). Both idempotent, REP=3 internally.
  hipLaunchKernelGGL(mainA_kernel, dim3(N_PTS / 128), dim3(512), 0, stream,
                     x, grid, W1, b1, wsB, out);
  hipLaunchKernelGGL(mainB_kernel, dim3(N_PTS / 64), dim3(256), 0, stream,
                     x, grid, W1, b1, wsB, out);
}

// Round 18
// 35.250 us; speedup vs baseline: 22.6625x; 22.6625x over previous
//
#include <hip/hip_runtime.h>
#include <hip/hip_fp16.h>

typedef _Float16 f16x8 __attribute__((ext_vector_type(8)));
typedef float f32x4 __attribute__((ext_vector_type(4)));

#define N_PTS 32768
#define ROWS 64
#define X_STRIDE 72
#define P_STRIDE 68

template <int V> struct ic { static constexpr int value = V; };

// ---- prep: repack W2 + b2 into f16 MFMA fragment layout (R6-proven).
// 130 blocks: c = bid>>1, half u = bid&1 (R14-verified variant).
__global__ __launch_bounds__(256) void prep_kernel(
    const float* __restrict__ W2, const float* __restrict__ b2,
    _Float16* __restrict__ wsB) {
  __shared__ _Float16 w_lds[64][X_STRIDE];
  const int c   = blockIdx.x >> 1;
  const int u   = blockIdx.x & 1;
  const int tid = threadIdx.x;
  {
    const float* src = (c < 64) ? (W2 + c * 4096 + tid * 16) : (b2 + tid * 16);
    int kl = tid >> 2, o = (tid & 3) * 16;
    f16x8 v0, v1;
    #pragma unroll
    for (int j = 0; j < 8; ++j) {
      v0[j] = (_Float16)src[j];
      v1[j] = (_Float16)src[8 + j];
    }
    *(f16x8*)(&w_lds[kl][o])     = v0;
    *(f16x8*)(&w_lds[kl][o + 8]) = v1;
  }
  __syncthreads();
  {
    int t = tid + u * 256;
    int q = t >> 6, lane = t & 63;
    int klbase = (q >> 2) * 32 + ((lane >> 4) & 3) * 8;
    int o      = (q & 3) * 16 + (lane & 15);
    f16x8 v;
    #pragma unroll
    for (int j = 0; j < 8; ++j) v[j] = w_lds[klbase + j][o];
    *(f16x8*)(wsB + c * 4096 + t * 8) = v;
  }
}

// ---- main: R12 base + block-staggered chunk order + 4-deep prefetch ----
// 512 blocks x 256 threads (4 waves, K-split), 2 blocks/CU. Odd blocks walk
// chunk positions 8..15,0..7 (even: 0..15): de-convoys L2 sector access
// across CUs while same-CU block pairs (bid, bid+256: same parity) keep
// identical order for L1 sharing. 4 register B buffers (depth-3 prefetch).
__global__ __launch_bounds__(256) void main_kernel(
    const float* __restrict__ x, const float* __restrict__ gridp,
    const float* __restrict__ W1, const float* __restrict__ b1,
    const _Float16* __restrict__ wsB, float* __restrict__ out) {

  __shared__ _Float16 h_t[4][ROWS][16];        // 8192 B
  __shared__ float part[4][ROWS * P_STRIDE];   // 69632 B; total 77824 -> 2/CU
  _Float16* x_lds = (_Float16*)&part[0][0];    // [64][X_STRIDE]; dead before part

  const int tid  = threadIdx.x;
  const int lane = tid & 63;
  const int wave = tid >> 6;
  const int rowblk = blockIdx.x * ROWS;

  // phase 0: coalesced x-tile load (16 consecutive f32 per thread)
  const float* xsrc = x + rowblk * 64 + tid * 16;
  f32x4 xr0 = *(const f32x4*)(xsrc);
  f32x4 xr1 = *(const f32x4*)(xsrc + 4);
  f32x4 xr2 = *(const f32x4*)(xsrc + 8);
  f32x4 xr3 = *(const f32x4*)(xsrc + 12);

  // phase 1: h = gelu(grid@W1+b1), tanh-form. k = w4 + 4q -> h_t[w4][row][q]
  {
    int row = tid >> 2;
    int w4  = tid & 3;
    int r = rowblk + row;
    float g0 = gridp[r * 3 + 0], g1 = gridp[r * 3 + 1], g2 = gridp[r * 3 + 2];
    f16x8 h0, h1;
    #pragma unroll
    for (int q = 0; q < 16; ++q) {
      int k = w4 + 4 * q;
      float v = g0 * W1[k] + g1 * W1[64 + k] + g2 * W1[128 + k] + b1[k];
      float v2 = v * v;
      float u  = v * fmaf(0.044715f, v2, 1.0f);
      float e  = __builtin_amdgcn_exp2f(u * 2.3022084f);
      float rr = e + 1.0f;
      float inv;
      asm("v_rcp_f32 %0, %1" : "=v"(inv) : "v"(rr));
      float h = v * (1.0f - inv);
      if (q < 8) h0[q] = (_Float16)h; else h1[q - 8] = (_Float16)h;
    }
    *(f16x8*)(&h_t[w4][row][0]) = h0;
    *(f16x8*)(&h_t[w4][row][8]) = h1;
  }

  // phase 2: x -> f16 -> LDS
  {
    int row = tid >> 2, o = (tid & 3) * 16;
    f16x8 v0, v1;
    #pragma unroll
    for (int j = 0; j < 4; ++j) {
      v0[j]     = (_Float16)xr0[j];
      v0[4 + j] = (_Float16)xr1[j];
      v1[j]     = (_Float16)xr2[j];
      v1[4 + j] = (_Float16)xr3[j];
    }
    *(f16x8*)(&x_lds[row * X_STRIDE + o])     = v0;
    *(f16x8*)(&x_lds[row * X_STRIDE + o + 8]) = v1;
  }
  __syncthreads();

  const int mrow = lane & 15;
  const int kgrp = lane >> 4;
  const _Float16* bp = wsB + lane * 8;

  auto LOADB = [&](f16x8* b, int c) {
    #pragma unroll
    for (int q = 0; q < 8; ++q)
      b[q] = *(const f16x8*)(bp + (c * 8 + q) * 512);
  };

  f16x8 buf0[8], buf1[8], buf2[8], buf3[8];

  // h rows -> registers
  f16x8 hreg[4][2];
  #pragma unroll
  for (int m = 0; m < 4; ++m) {
    hreg[m][0] = *(const f16x8*)(&h_t[wave][m * 16 + mrow][0]);
    hreg[m][1] = *(const f16x8*)(&h_t[wave][m * 16 + mrow][8]);
  }

  // x fragments from LDS
  f16x8 xf[4][2];
  #pragma unroll
  for (int m = 0; m < 4; ++m)
    #pragma unroll
    for (int s = 0; s < 2; ++s)
      xf[m][s] = *(const f16x8*)(&x_lds[(m * 16 + mrow) * X_STRIDE + s * 32 + kgrp * 8]);

  f32x4 acc[4][4];
  #pragma unroll
  for (int m = 0; m < 4; ++m)
    #pragma unroll
    for (int n = 0; n < 4; ++n)
      acc[m][n] = (f32x4){0.f, 0.f, 0.f, 0.f};

  auto COMPUTE = [&](const f16x8* b, int p) {   // p static after unroll
    #pragma unroll
    for (int m = 0; m < 4; ++m) {
      _Float16 hh = hreg[m][p >> 3][p & 7];
      f16x8 hs = {hh, hh, hh, hh, hh, hh, hh, hh};
      f16x8 a0 = xf[m][0] * hs;
      f16x8 a1 = xf[m][1] * hs;
      #pragma unroll
      for (int n = 0; n < 4; ++n) {
        acc[m][n] = __builtin_amdgcn_mfma_f32_16x16x32_f16(a0, b[n],     acc[m][n], 0, 0, 0);
        acc[m][n] = __builtin_amdgcn_mfma_f32_16x16x32_f16(a1, b[4 + n], acc[m][n], 0, 0, 0);
      }
    }
  };

  // K-loop, 4-buffer rotation, prefetch distance 3, block-staggered order.
  auto runloop = [&](auto p0c) {
    constexpr int P0 = decltype(p0c)::value;
    auto P = [](int i) { return ((i + P0) & 15); };
    f16x8* bufs[4] = {buf0, buf1, buf2, buf3};   // indexed statically below
    LOADB(buf0, wave + 4 * P(0));
    LOADB(buf1, wave + 4 * P(1));
    LOADB(buf2, wave + 4 * P(2));
    #pragma unroll
    for (int i = 0; i < 16; ++i) {
      f16x8* cur = bufs[i & 3];           // i static -> static selection
      COMPUTE(cur, P(i));
      if (i + 3 < 16) {
        LOADB(bufs[(i + 3) & 3], wave + 4 * P(i + 3));
      } else if (i == 13 && wave == 0) {
        LOADB(bufs[0], 64);               // bias chunk into freed buf0
      }
    }
    if (wave == 0) {                      // bias (h == 1): A = xf directly
      #pragma unroll
      for (int m = 0; m < 4; ++m)
        #pragma unroll
        for (int n = 0; n < 4; ++n) {
          acc[m][n] = __builtin_amdgcn_mfma_f32_16x16x32_f16(xf[m][0], buf0[n],     acc[m][n], 0, 0, 0);
          acc[m][n] = __builtin_amdgcn_mfma_f32_16x16x32_f16(xf[m][1], buf0[4 + n], acc[m][n], 0, 0, 0);
        }
    }
  };
  if (blockIdx.x & 1) runloop(ic<8>{});
  else                runloop(ic<0>{});

  __syncthreads();   // K-loop done; x_lds dead -> part writable

  {
    float* pw = part[wave];
    #pragma unroll
    for (int m = 0; m < 4; ++m)
      #pragma unroll
      for (int n = 0; n < 4; ++n)
        #pragma unroll
        for (int r = 0; r < 4; ++r)
          pw[(m * 16 + kgrp * 4 + r) * P_STRIDE + n * 16 + mrow] = acc[m][n][r];
  }
  __syncthreads();

  {
    int row = tid >> 2;
    int cb  = (tid & 3) * 16;
    const float* p0 = part[0] + row * P_STRIDE + cb;
    float* op = out + (rowblk + row) * 64 + cb;
    #pragma unroll
    for (int j = 0; j < 4; ++j) {
      f32x4 s = *(const f32x4*)(p0 + j * 4);
      #pragma unroll
      for (int w = 1; w < 4; ++w)
        s += *(const f32x4*)(p0 + w * (ROWS * P_STRIDE) + j * 4);
      *(f32x4*)(op + j * 4) = s;
    }
  }
}

extern "C" void kernel_launch(void* const* d_in, const int* in_sizes, int n_in,
                              void* d_out, int out_size, void* d_ws, size_t ws_size,
                              hipStream_t stream) {
  const float* x    = (const float*)d_in[0];
  const float* grid = (const float*)d_in[1];
  const float* W1   = (const float*)d_in[2];
  const float* b1   = (const float*)d_in[3];
  const float* W2   = (const float*)d_in[4];
  const float* b2   = (const float*)d_in[5];
  float* out = (float*)d_out;
  _Float16* wsB = (_Float16*)d_ws;   // 65*4096*2 = 532480 bytes

  hipLaunchKernelGGL(prep_kernel, dim3(130), dim3(256), 0, stream,
                     W2, b2, wsB);
  hipLaunchKernelGGL(main_kernel, dim3(N_PTS / ROWS), dim3(256), 0, stream,
                     x, grid, W1, b1, wsB, out);
}

// Round 19
// 35.132 us; speedup vs baseline: 22.7386x; 1.0034x over previous
//
#include <hip/hip_runtime.h>
#include <hip/hip_fp16.h>

typedef _Float16 f16x8 __attribute__((ext_vector_type(8)));
typedef float f32x4 __attribute__((ext_vector_type(4)));

#define N_PTS 32768
#define ROWS 64
#define X_STRIDE 72
#define P_STRIDE 68

// ---- prep: repack W2 + b2 into f16 MFMA fragment layout (R6-proven).
// 130 blocks: c = bid>>1, half u = bid&1.
__global__ __launch_bounds__(256) void prep_kernel(
    const float* __restrict__ W2, const float* __restrict__ b2,
    _Float16* __restrict__ wsB) {
  __shared__ _Float16 w_lds[64][X_STRIDE];
  const int c   = blockIdx.x >> 1;
  const int u   = blockIdx.x & 1;
  const int tid = threadIdx.x;
  {
    const float* src = (c < 64) ? (W2 + c * 4096 + tid * 16) : (b2 + tid * 16);
    int kl = tid >> 2, o = (tid & 3) * 16;
    f16x8 v0, v1;
    #pragma unroll
    for (int j = 0; j < 8; ++j) {
      v0[j] = (_Float16)src[j];
      v1[j] = (_Float16)src[8 + j];
    }
    *(f16x8*)(&w_lds[kl][o])     = v0;
    *(f16x8*)(&w_lds[kl][o + 8]) = v1;
  }
  __syncthreads();
  {
    int t = tid + u * 256;
    int q = t >> 6, lane = t & 63;
    int klbase = (q >> 2) * 32 + ((lane >> 4) & 3) * 8;
    int o      = (q & 3) * 16 + (lane & 15);
    f16x8 v;
    #pragma unroll
    for (int j = 0; j < 8; ++j) v[j] = w_lds[klbase + j][o];
    *(f16x8*)(wsB + c * 4096 + t * 8) = v;
  }
}

// ---- main: R12 exact (best: 30.3) with ONE change: COMPUTE reordered so
// same-accumulator MFMAs are 16 apart (was adjacent dependent pairs ->
// ~20-30 cyc stall x 16 pairs x 16 chunks per wave = the hidden 4x).
__global__ __launch_bounds__(256) void main_kernel(
    const float* __restrict__ x, const float* __restrict__ gridp,
    const float* __restrict__ W1, const float* __restrict__ b1,
    const _Float16* __restrict__ wsB, float* __restrict__ out) {

  __shared__ _Float16 h_t[4][ROWS][16];        // 8192 B
  __shared__ float part[4][ROWS * P_STRIDE];   // 69632 B; total 77824 -> 2/CU
  _Float16* x_lds = (_Float16*)&part[0][0];    // [64][X_STRIDE]; dead before part

  const int tid  = threadIdx.x;
  const int lane = tid & 63;
  const int wave = tid >> 6;
  const int rowblk = blockIdx.x * ROWS;

  // phase 0: coalesced x-tile load (16 consecutive f32 per thread)
  const float* xsrc = x + rowblk * 64 + tid * 16;
  f32x4 xr0 = *(const f32x4*)(xsrc);
  f32x4 xr1 = *(const f32x4*)(xsrc + 4);
  f32x4 xr2 = *(const f32x4*)(xsrc + 8);
  f32x4 xr3 = *(const f32x4*)(xsrc + 12);

  // phase 1: h = gelu(grid@W1+b1), tanh-form. k = w4 + 4q -> h_t[w4][row][q]
  {
    int row = tid >> 2;
    int w4  = tid & 3;
    int r = rowblk + row;
    float g0 = gridp[r * 3 + 0], g1 = gridp[r * 3 + 1], g2 = gridp[r * 3 + 2];
    f16x8 h0, h1;
    #pragma unroll
    for (int q = 0; q < 16; ++q) {
      int k = w4 + 4 * q;
      float v = g0 * W1[k] + g1 * W1[64 + k] + g2 * W1[128 + k] + b1[k];
      float v2 = v * v;
      float u  = v * fmaf(0.044715f, v2, 1.0f);
      float e  = __builtin_amdgcn_exp2f(u * 2.3022084f);
      float rr = e + 1.0f;
      float inv;
      asm("v_rcp_f32 %0, %1" : "=v"(inv) : "v"(rr));
      float h = v * (1.0f - inv);
      if (q < 8) h0[q] = (_Float16)h; else h1[q - 8] = (_Float16)h;
    }
    *(f16x8*)(&h_t[w4][row][0]) = h0;
    *(f16x8*)(&h_t[w4][row][8]) = h1;
  }

  // phase 2: x -> f16 -> LDS
  {
    int row = tid >> 2, o = (tid & 3) * 16;
    f16x8 v0, v1;
    #pragma unroll
    for (int j = 0; j < 4; ++j) {
      v0[j]     = (_Float16)xr0[j];
      v0[4 + j] = (_Float16)xr1[j];
      v1[j]     = (_Float16)xr2[j];
      v1[4 + j] = (_Float16)xr3[j];
    }
    *(f16x8*)(&x_lds[row * X_STRIDE + o])     = v0;
    *(f16x8*)(&x_lds[row * X_STRIDE + o + 8]) = v1;
  }
  __syncthreads();

  const int mrow = lane & 15;
  const int kgrp = lane >> 4;
  const _Float16* bp = wsB + lane * 8;

  auto LOADB = [&](f16x8* b, int c) {
    #pragma unroll
    for (int q = 0; q < 8; ++q)
      b[q] = *(const f16x8*)(bp + (c * 8 + q) * 512);
  };

  // issue first B batches before LDS reads
  f16x8 bA[8], bB[8], bC[8];
  LOADB(bA, wave);
  LOADB(bB, wave + 4);
  LOADB(bC, wave + 8);

  // h rows -> registers
  f16x8 hreg[4][2];
  #pragma unroll
  for (int m = 0; m < 4; ++m) {
    hreg[m][0] = *(const f16x8*)(&h_t[wave][m * 16 + mrow][0]);
    hreg[m][1] = *(const f16x8*)(&h_t[wave][m * 16 + mrow][8]);
  }

  // x fragments from LDS
  f16x8 xf[4][2];
  #pragma unroll
  for (int m = 0; m < 4; ++m)
    #pragma unroll
    for (int s = 0; s < 2; ++s)
      xf[m][s] = *(const f16x8*)(&x_lds[(m * 16 + mrow) * X_STRIDE + s * 32 + kgrp * 8]);

  f32x4 acc[4][4];
  #pragma unroll
  for (int m = 0; m < 4; ++m)
    #pragma unroll
    for (int n = 0; n < 4; ++n)
      acc[m][n] = (f32x4){0.f, 0.f, 0.f, 0.f};

  // REORDERED COMPUTE: all a-frags first, then 16 independent s=0 MFMAs,
  // then 16 s=1 MFMAs. Same-acc dependency distance: 16 (was 1).
  auto COMPUTE = [&](const f16x8* b, int p) {   // p static after unroll
    f16x8 a0[4], a1[4];
    #pragma unroll
    for (int m = 0; m < 4; ++m) {
      _Float16 hh = hreg[m][p >> 3][p & 7];
      f16x8 hs = {hh, hh, hh, hh, hh, hh, hh, hh};
      a0[m] = xf[m][0] * hs;
      a1[m] = xf[m][1] * hs;
    }
    #pragma unroll
    for (int m = 0; m < 4; ++m)
      #pragma unroll
      for (int n = 0; n < 4; ++n)
        acc[m][n] = __builtin_amdgcn_mfma_f32_16x16x32_f16(a0[m], b[n], acc[m][n], 0, 0, 0);
    #pragma unroll
    for (int m = 0; m < 4; ++m)
      #pragma unroll
      for (int n = 0; n < 4; ++n)
        acc[m][n] = __builtin_amdgcn_mfma_f32_16x16x32_f16(a1[m], b[4 + n], acc[m][n], 0, 0, 0);
  };
  auto COMPUTE_BIAS = [&](const f16x8* b) {     // h == 1: A = xf directly
    #pragma unroll
    for (int m = 0; m < 4; ++m)
      #pragma unroll
      for (int n = 0; n < 4; ++n)
        acc[m][n] = __builtin_amdgcn_mfma_f32_16x16x32_f16(xf[m][0], b[n], acc[m][n], 0, 0, 0);
    #pragma unroll
    for (int m = 0; m < 4; ++m)
      #pragma unroll
      for (int n = 0; n < 4; ++n)
        acc[m][n] = __builtin_amdgcn_mfma_f32_16x16x32_f16(xf[m][1], b[4 + n], acc[m][n], 0, 0, 0);
  };

  // K-loop: positions p = 0..15 (c = wave + 4p), 3-buffer rotation, static.
  #pragma unroll
  for (int g = 0; g < 5; ++g) {
    COMPUTE(bA, 3 * g);
    if (3 * g + 3 < 16) LOADB(bA, wave + 4 * (3 * g + 3));
    COMPUTE(bB, 3 * g + 1);
    if (3 * g + 4 < 16) LOADB(bB, wave + 4 * (3 * g + 4));
    else if (wave == 0) LOADB(bB, 64);       // bias-chunk B, issued early
    COMPUTE(bC, 3 * g + 2);
    if (3 * g + 5 < 16) LOADB(bC, wave + 4 * (3 * g + 5));
  }
  COMPUTE(bA, 15);
  if (wave == 0) COMPUTE_BIAS(bB);

  __syncthreads();   // K-loop done; x_lds dead -> part writable

  // one-stage reduce: every wave writes its partial buffer...
  {
    float* pw = part[wave];
    #pragma unroll
    for (int m = 0; m < 4; ++m)
      #pragma unroll
      for (int n = 0; n < 4; ++n)
        #pragma unroll
        for (int r = 0; r < 4; ++r)
          pw[(m * 16 + kgrp * 4 + r) * P_STRIDE + n * 16 + mrow] = acc[m][n][r];
  }
  __syncthreads();

  // ...then all 256 threads sum 4 buffers and store (4 threads/row, 16 cols)
  {
    int row = tid >> 2;
    int cb  = (tid & 3) * 16;
    const float* p0 = part[0] + row * P_STRIDE + cb;
    float* op = out + (rowblk + row) * 64 + cb;
    #pragma unroll
    for (int j = 0; j < 4; ++j) {
      f32x4 s = *(const f32x4*)(p0 + j * 4);
      #pragma unroll
      for (int w = 1; w < 4; ++w)
        s += *(const f32x4*)(p0 + w * (ROWS * P_STRIDE) + j * 4);
      *(f32x4*)(op + j * 4) = s;
    }
  }
}

extern "C" void kernel_launch(void* const* d_in, const int* in_sizes, int n_in,
                              void* d_out, int out_size, void* d_ws, size_t ws_size,
                              hipStream_t stream) {
  const float* x    = (const float*)d_in[0];
  const float* grid = (const float*)d_in[1];
  const float* W1   = (const float*)d_in[2];
  const float* b1   = (const float*)d_in[3];
  const float* W2   = (const float*)d_in[4];
  const float* b2   = (const float*)d_in[5];
  float* out = (float*)d_out;
  _Float16* wsB = (_Float16*)d_ws;   // 65*4096*2 = 532480 bytes

  hipLaunchKernelGGL(prep_kernel, dim3(130), dim3(256), 0, stream,
                     W2, b2, wsB);
  hipLaunchKernelGGL(main_kernel, dim3(N_PTS / ROWS), dim3(256), 0, stream,
                     x, grid, W1, b1, wsB, out);
}

// Round 20
// 29.581 us; speedup vs baseline: 27.0057x; 1.1877x over previous
//
#include <hip/hip_runtime.h>
#include <hip/hip_fp16.h>

typedef _Float16 f16x8 __attribute__((ext_vector_type(8)));
typedef _Float16 f16x4v __attribute__((ext_vector_type(4)));
typedef float f32x4 __attribute__((ext_vector_type(4)));

#define N_PTS 32768
#define ROWS 64
#define X_STRIDE 72     // f16; 144 B rows: 16B-aligned b128, reads 2-way max
#define P_STRIDE 68     // f32; 272 B rows: 16B-aligned

// ---- prep: repack W2 + b2 into f16 MFMA fragment layout (R6-proven pattern,
// R14-verified 130-block split: c = bid>>1, half u = bid&1).
__global__ __launch_bounds__(256) void prep_kernel(
    const float* __restrict__ W2, const float* __restrict__ b2,
    _Float16* __restrict__ wsB) {
  __shared__ _Float16 w_lds[64][X_STRIDE];
  const int c   = blockIdx.x >> 1;
  const int u   = blockIdx.x & 1;
  const int tid = threadIdx.x;
  {
    const float* src = (c < 64) ? (W2 + c * 4096 + tid * 16) : (b2 + tid * 16);
    int kl = tid >> 2, o = (tid & 3) * 16;
    f16x8 v0, v1;
    #pragma unroll
    for (int j = 0; j < 8; ++j) {
      v0[j] = (_Float16)src[j];
      v1[j] = (_Float16)src[8 + j];
    }
    *(f16x8*)(&w_lds[kl][o])     = v0;
    *(f16x8*)(&w_lds[kl][o + 8]) = v1;
  }
  __syncthreads();
  {
    int t = tid + u * 256;
    int q = t >> 6, lane = t & 63;
    int klbase = (q >> 2) * 32 + ((lane >> 4) & 3) * 8;
    int o      = (q & 3) * 16 + (lane & 15);
    f16x8 v;
    #pragma unroll
    for (int j = 0; j < 8; ++j) v[j] = w_lds[klbase + j][o];
    *(f16x8*)(wsB + c * 4096 + t * 8) = v;
  }
}

// ---- main: R12 VERBATIM (champion: 30.3 us total across 20 rounds) ----
// 512 blocks x 256 threads (4 waves), 2 blocks/CU. Waves K-split 65 chunks
// (wave w: c = w + 4i, i = 0..15; wave 0 also bias c = 64). Triple-buffered
// register B stream; h in registers (compile-time extraction from hreg).
__global__ __launch_bounds__(256) void main_kernel(
    const float* __restrict__ x, const float* __restrict__ gridp,
    const float* __restrict__ W1, const float* __restrict__ b1,
    const _Float16* __restrict__ wsB, float* __restrict__ out) {

  __shared__ _Float16 h_t[4][ROWS][16];        // 8192 B: h_t[w][row][i] = h[row][w+4i]
  __shared__ float part[4][ROWS * P_STRIDE];   // 69632 B; total 77824 -> 2/CU
  _Float16* x_lds = (_Float16*)&part[0][0];    // [64][X_STRIDE]; dead before part

  const int tid  = threadIdx.x;
  const int lane = tid & 63;
  const int wave = tid >> 6;
  const int rowblk = blockIdx.x * ROWS;

  // phase 0: issue coalesced x-tile load (16 consecutive f32 per thread)
  const float* xsrc = x + rowblk * 64 + tid * 16;
  f32x4 xr0 = *(const f32x4*)(xsrc);
  f32x4 xr1 = *(const f32x4*)(xsrc + 4);
  f32x4 xr2 = *(const f32x4*)(xsrc + 8);
  f32x4 xr3 = *(const f32x4*)(xsrc + 12);

  // phase 1: h. Thread (row = tid>>2, w4 = tid&3) computes the k-set of wave
  // w4: k = w4 + 4q, q = 0..15 -> h_t[w4][row][q]. Two b128 writes, no scatter.
  {
    int row = tid >> 2;
    int w4  = tid & 3;
    int r = rowblk + row;
    float g0 = gridp[r * 3 + 0], g1 = gridp[r * 3 + 1], g2 = gridp[r * 3 + 2];
    f16x8 h0, h1;
    #pragma unroll
    for (int q = 0; q < 16; ++q) {
      int k = w4 + 4 * q;
      float v = g0 * W1[k] + g1 * W1[64 + k] + g2 * W1[128 + k] + b1[k];
      float v2 = v * v;
      float pp = fmaf(0.044715f, v2, 1.0f);
      float u  = v * pp;                    // v + 0.044715 v^3
      float e  = __builtin_amdgcn_exp2f(u * 2.3022084f);  // e^{1.59577*u}
      float rr = e + 1.0f;
      float inv;
      asm("v_rcp_f32 %0, %1" : "=v"(inv) : "v"(rr));
      float h = v * (1.0f - inv);           // 0.5v(1+tanh(.)) == v(1-1/(e+1))
      if (q < 8) h0[q] = (_Float16)h; else h1[q - 8] = (_Float16)h;
    }
    *(f16x8*)(&h_t[w4][row][0]) = h0;
    *(f16x8*)(&h_t[w4][row][8]) = h1;
  }

  // phase 2: x -> f16 -> LDS (coalesced-in, b128 LDS writes)
  {
    int row = tid >> 2, o = (tid & 3) * 16;
    f16x8 v0, v1;
    #pragma unroll
    for (int j = 0; j < 4; ++j) {
      v0[j]     = (_Float16)xr0[j];
      v0[4 + j] = (_Float16)xr1[j];
      v1[j]     = (_Float16)xr2[j];
      v1[4 + j] = (_Float16)xr3[j];
    }
    *(f16x8*)(&x_lds[row * X_STRIDE + o])     = v0;
    *(f16x8*)(&x_lds[row * X_STRIDE + o + 8]) = v1;
  }
  __syncthreads();

  const int mrow = lane & 15;        // A row within 16-tile / D col
  const int kgrp = lane >> 4;        // 0..3
  const _Float16* bp = wsB + lane * 8;

  auto LOADB = [&](f16x8* b, int c) {
    #pragma unroll
    for (int q = 0; q < 8; ++q)
      b[q] = *(const f16x8*)(bp + (c * 8 + q) * 512);
  };

  // issue first B batches before LDS reads (overlap global latency)
  f16x8 bA[8], bB[8], bC[8];
  LOADB(bA, wave);
  LOADB(bB, wave + 4);
  LOADB(bC, wave + 8);

  // h rows -> registers: hreg[m][half] covers chunk positions 0..15
  f16x8 hreg[4][2];
  #pragma unroll
  for (int m = 0; m < 4; ++m) {
    hreg[m][0] = *(const f16x8*)(&h_t[wave][m * 16 + mrow][0]);
    hreg[m][1] = *(const f16x8*)(&h_t[wave][m * 16 + mrow][8]);
  }

  // x fragments from LDS
  f16x8 xf[4][2];
  #pragma unroll
  for (int m = 0; m < 4; ++m)
    #pragma unroll
    for (int s = 0; s < 2; ++s)
      xf[m][s] = *(const f16x8*)(&x_lds[(m * 16 + mrow) * X_STRIDE + s * 32 + kgrp * 8]);

  f32x4 acc[4][4];
  #pragma unroll
  for (int m = 0; m < 4; ++m)
    #pragma unroll
    for (int n = 0; n < 4; ++n)
      acc[m][n] = (f32x4){0.f, 0.f, 0.f, 0.f};

  // COMPUTE for chunk position p (STATIC after unroll): h from registers.
  auto COMPUTE = [&](const f16x8* b, int p) {
    #pragma unroll
    for (int m = 0; m < 4; ++m) {
      _Float16 hh = hreg[m][p >> 3][p & 7];   // compile-time extraction
      f16x8 hs = {hh, hh, hh, hh, hh, hh, hh, hh};
      f16x8 a0 = xf[m][0] * hs;
      f16x8 a1 = xf[m][1] * hs;
      #pragma unroll
      for (int n = 0; n < 4; ++n) {
        acc[m][n] = __builtin_amdgcn_mfma_f32_16x16x32_f16(a0, b[n],     acc[m][n], 0, 0, 0);
        acc[m][n] = __builtin_amdgcn_mfma_f32_16x16x32_f16(a1, b[4 + n], acc[m][n], 0, 0, 0);
      }
    }
  };
  auto COMPUTE_BIAS = [&](const f16x8* b) {   // h == 1: A-frag = xf directly
    #pragma unroll
    for (int m = 0; m < 4; ++m)
      #pragma unroll
      for (int n = 0; n < 4; ++n) {
        acc[m][n] = __builtin_amdgcn_mfma_f32_16x16x32_f16(xf[m][0], b[n],     acc[m][n], 0, 0, 0);
        acc[m][n] = __builtin_amdgcn_mfma_f32_16x16x32_f16(xf[m][1], b[4 + n], acc[m][n], 0, 0, 0);
      }
  };

  // K-loop: positions p = 0..15 (c = wave + 4p), 3-buffer rotation, static.
  #pragma unroll
  for (int g = 0; g < 5; ++g) {
    COMPUTE(bA, 3 * g);
    if (3 * g + 3 < 16) LOADB(bA, wave + 4 * (3 * g + 3));
    COMPUTE(bB, 3 * g + 1);
    if (3 * g + 4 < 16) LOADB(bB, wave + 4 * (3 * g + 4));
    else if (wave == 0) LOADB(bB, 64);       // bias-chunk B, issued early
    COMPUTE(bC, 3 * g + 2);
    if (3 * g + 5 < 16) LOADB(bC, wave + 4 * (3 * g + 5));
  }
  COMPUTE(bA, 15);
  if (wave == 0) COMPUTE_BIAS(bB);

  __syncthreads();   // K-loop done everywhere; x_lds dead -> part writable

  // one-stage reduce: every wave writes its partial buffer...
  {
    float* pw = part[wave];
    #pragma unroll
    for (int m = 0; m < 4; ++m)
      #pragma unroll
      for (int n = 0; n < 4; ++n)
        #pragma unroll
        for (int r = 0; r < 4; ++r)
          pw[(m * 16 + kgrp * 4 + r) * P_STRIDE + n * 16 + mrow] = acc[m][n][r];
  }
  __syncthreads();

  // ...then all 256 threads sum 4 buffers and store (4 threads/row, 16 cols)
  {
    int row = tid >> 2;
    int cb  = (tid & 3) * 16;
    const float* p0 = part[0] + row * P_STRIDE + cb;
    float* op = out + (rowblk + row) * 64 + cb;
    #pragma unroll
    for (int j = 0; j < 4; ++j) {
      f32x4 s = *(const f32x4*)(p0 + j * 4);
      #pragma unroll
      for (int w = 1; w < 4; ++w)
        s += *(const f32x4*)(p0 + w * (ROWS * P_STRIDE) + j * 4);
      *(f32x4*)(op + j * 4) = s;
    }
  }
}

extern "C" void kernel_launch(void* const* d_in, const int* in_sizes, int n_in,
                              void* d_out, int out_size, void* d_ws, size_t ws_size,
                              hipStream_t stream) {
  const float* x    = (const float*)d_in[0];
  const float* grid = (const float*)d_in[1];
  const float* W1   = (const float*)d_in[2];
  const float* b1   = (const float*)d_in[3];
  const float* W2   = (const float*)d_in[4];
  const float* b2   = (const float*)d_in[5];
  float* out = (float*)d_out;
  _Float16* wsB = (_Float16*)d_ws;   // 65*4096*2 = 532480 bytes

  hipLaunchKernelGGL(prep_kernel, dim3(130), dim3(256), 0, stream,
                     W2, b2, wsB);
  hipLaunchKernelGGL(main_kernel, dim3(N_PTS / ROWS), dim3(256), 0, stream,
                     x, grid, W1, b1, wsB, out);
}